// Round 6
// baseline (432.982 us; speedup 1.0000x reference)
//
#include <hip/hip_runtime.h>
#include <cstdint>
#include <cstddef>

#define EPSV 1e-5f
#define NPIX 9216          // 96*96
#define LDA 136            // padded bf16 k-stride for 128-wide K chunks
#define LDK 72             // padded bf16 k-stride for 64-wide K chunks
#define SPX 66             // S px-stride (64 px + 2 pad), fp16

typedef __bf16 bf16;
typedef __attribute__((ext_vector_type(8))) __bf16 bf16x8;
typedef __attribute__((ext_vector_type(4))) __bf16 bf16x4;
typedef __attribute__((ext_vector_type(4))) float  f32x4;

__device__ __forceinline__ float silu_f(float v) { return v / (1.f + __expf(-v)); }

// ---------------------------------------------------------------------------
// WTSf (float, 608): b1[128] | b1b[128] | b2[128] | bom[224]
// WTSb (bf16, 249856), all [co][ci]:
//   0       W1b  [128][256]  (x1 1x1, BN-folded)
//   32768   W1bb [128][64]   (x2 1x1, BN-folded)
//   40960   W2b  [9][128][128] (3x3 s2, BN-folded, k-major)
//   188416  Wipb [128][128]
//   204800  Womb [224][128]  (rows 216..223 zero)
//   233472  Wopb [128][128]
// ---------------------------------------------------------------------------
__global__ __launch_bounds__(256) void prep_kernel(
    const float* __restrict__ conv_w, const float* __restrict__ conv_g,
    const float* __restrict__ conv_b, const float* __restrict__ conv_rm, const float* __restrict__ conv_rv,
    const float* __restrict__ conv1_w, const float* __restrict__ conv1_g,
    const float* __restrict__ conv1_b, const float* __restrict__ conv1_rm, const float* __restrict__ conv1_rv,
    const float* __restrict__ conv2_w, const float* __restrict__ conv2_g,
    const float* __restrict__ conv2_bb, const float* __restrict__ conv2_rm, const float* __restrict__ conv2_rv,
    const float* __restrict__ ip_w, const float* __restrict__ op_w,
    const float* __restrict__ off_w, const float* __restrict__ m_w,
    const float* __restrict__ off_b, const float* __restrict__ m_b,
    float* __restrict__ WTSf, bf16* __restrict__ WTSb)
{
  int idx = blockIdx.x * 256 + threadIdx.x;
  if (idx < 608) {
    if (idx < 128) {
      int co = idx;
      float s = conv_g[co] * rsqrtf(conv_rv[co] + EPSV);
      WTSf[idx] = conv_b[co] - conv_rm[co] * s;
    } else if (idx < 256) {
      int co = idx - 128;
      float s = conv1_g[co] * rsqrtf(conv1_rv[co] + EPSV);
      WTSf[idx] = conv1_b[co] - conv1_rm[co] * s;
    } else if (idx < 384) {
      int co = idx - 256;
      float s = conv2_g[co] * rsqrtf(conv2_rv[co] + EPSV);
      WTSf[idx] = conv2_bb[co] - conv2_rm[co] * s;
    } else {
      int col = idx - 384;
      WTSf[idx] = (col < 144) ? off_b[col] : (col < 216 ? m_b[col - 144] : 0.f);
    }
  } else {
    int j = idx - 608;
    if (j < 32768) {
      int co = j >> 8, ci = j & 255;
      float s = conv_g[co] * rsqrtf(conv_rv[co] + EPSV);
      WTSb[j] = (bf16)(conv_w[co * 256 + ci] * s);
    } else if (j < 40960) {
      int r = j - 32768; int co = r >> 6, ci = r & 63;
      float s = conv1_g[co] * rsqrtf(conv1_rv[co] + EPSV);
      WTSb[j] = (bf16)(conv1_w[co * 64 + ci] * s);
    } else if (j < 188416) {
      int r = j - 40960; int kp = r >> 14; int rr = r & 16383;
      int co = rr >> 7, ci = rr & 127;
      float s = conv2_g[co] * rsqrtf(conv2_rv[co] + EPSV);
      WTSb[j] = (bf16)(conv2_w[(co * 128 + ci) * 9 + kp] * s);
    } else if (j < 204800) {
      int r = j - 188416; int co = r >> 7, ci = r & 127;
      WTSb[j] = (bf16)ip_w[co * 128 + ci];
    } else if (j < 233472) {
      int r = j - 204800; int co = r >> 7, ci = r & 127;
      float v = (co < 144) ? off_w[co * 128 + ci] : (co < 216 ? m_w[(co - 144) * 128 + ci] : 0.f);
      WTSb[j] = (bf16)v;
    } else if (j < 249856) {
      int r = j - 233472; int co = r >> 7, ci = r & 127;
      WTSb[j] = (bf16)op_w[co * 128 + ci];
    }
  }
}

// ---------------------------------------------------------------------------
// 1x1 conv via MFMA: NCHW fp32 (K ch) -> NHWC bf16 (128 ch) + BN + SiLU
// ---------------------------------------------------------------------------
__global__ __launch_bounds__(256) void c1x1_mfma_kernel(
    const float* __restrict__ x, const bf16* __restrict__ W,
    const float* __restrict__ bias, int K, int HW, bf16* __restrict__ outb)
{
  __shared__ bf16 As[64 * LDK];
  __shared__ bf16 Bs[128 * LDK];
  int m0 = blockIdx.x << 6;
  int t = threadIdx.x;
  int n = m0 / HW; int hw0 = m0 - n * HW;
  const float* xn = x + (size_t)n * K * HW;
  int wv = t >> 6, lane = t & 63;
  int lrow = lane & 15, q = lane >> 4;
  int n0 = wv * 32;
  f32x4 acc[4][2];
#pragma unroll
  for (int i = 0; i < 4; ++i)
#pragma unroll
    for (int j = 0; j < 2; ++j)
#pragma unroll
      for (int e = 0; e < 4; ++e) acc[i][j][e] = 0.f;

  for (int k0 = 0; k0 < K; k0 += 64) {
    if (k0) __syncthreads();
    for (int i = t; i < 1024; i += 256) {
      int px = i & 63; int ci4 = (i >> 6) << 2;
      bf16x4 p;
#pragma unroll
      for (int j = 0; j < 4; ++j)
        p[j] = (bf16)xn[(size_t)(k0 + ci4 + j) * HW + hw0 + px];
      *(bf16x4*)&As[px * LDK + ci4] = p;
    }
    for (int i = t; i < 1024; i += 256) {
      int co = i >> 3; int k8 = (i & 7) << 3;
      *(bf16x8*)&Bs[co * LDK + k8] = *(const bf16x8*)&W[(size_t)co * K + k0 + k8];
    }
    __syncthreads();
#pragma unroll
    for (int ks = 0; ks < 2; ++ks) {
      int ko = ks * 32 + q * 8;
      bf16x8 bfr0 = *(const bf16x8*)&Bs[(n0 + lrow) * LDK + ko];
      bf16x8 bfr1 = *(const bf16x8*)&Bs[(n0 + 16 + lrow) * LDK + ko];
#pragma unroll
      for (int mi = 0; mi < 4; ++mi) {
        bf16x8 afr = *(const bf16x8*)&As[(mi * 16 + lrow) * LDK + ko];
        acc[mi][0] = __builtin_amdgcn_mfma_f32_16x16x32_bf16(afr, bfr0, acc[mi][0], 0, 0, 0);
        acc[mi][1] = __builtin_amdgcn_mfma_f32_16x16x32_bf16(afr, bfr1, acc[mi][1], 0, 0, 0);
      }
    }
  }
#pragma unroll
  for (int mi = 0; mi < 4; ++mi) {
#pragma unroll
    for (int nj = 0; nj < 2; ++nj) {
      int co = n0 + nj * 16 + lrow;
      float bb = bias[co];
#pragma unroll
      for (int r = 0; r < 4; ++r) {
        int m = m0 + mi * 16 + q * 4 + r;
        outb[(size_t)m * 128 + co] = (bf16)silu_f(acc[mi][nj][r] + bb);
      }
    }
  }
}

// ---------------------------------------------------------------------------
// bilinear 2x upsample, NHWC bf16 -> bf16 ; thread = 4 channels
// ---------------------------------------------------------------------------
__global__ __launch_bounds__(256) void upsample_kernel(
    const bf16* __restrict__ y1b, bf16* __restrict__ feat1b)
{
  int idx = blockIdx.x * 256 + threadIdx.x;   // 1,179,648 total
  int c4 = (idx & 31) << 2;
  int pw = idx >> 5;
  int ow = pw % 96; int t1 = pw / 96;
  int oh = t1 % 96; int n = t1 / 96;
  float sh = oh * 0.5f - 0.25f, sw = ow * 0.5f - 0.25f;
  float hf = floorf(sh), wf = floorf(sw);
  float fy = sh - hf, fx = sw - wf;
  int h0 = (int)hf, w0 = (int)wf;
  int h0c = max(h0, 0), h1c = min(h0 + 1, 47);
  int w0c = max(w0, 0), w1c = min(w0 + 1, 47);
  const bf16* yn = y1b + (size_t)n * 2304 * 128 + c4;
  bf16x4 v00 = *(const bf16x4*)&yn[(h0c * 48 + w0c) * 128];
  bf16x4 v01 = *(const bf16x4*)&yn[(h0c * 48 + w1c) * 128];
  bf16x4 v10 = *(const bf16x4*)&yn[(h1c * 48 + w0c) * 128];
  bf16x4 v11 = *(const bf16x4*)&yn[(h1c * 48 + w1c) * 128];
  bf16x4 o;
#pragma unroll
  for (int e = 0; e < 4; ++e) {
    float v = (1.f - fy) * ((1.f - fx) * (float)v00[e] + fx * (float)v01[e])
            + fy * ((1.f - fx) * (float)v10[e] + fx * (float)v11[e]);
    o[e] = (bf16)v;
  }
  *(bf16x4*)&feat1b[((size_t)n * NPIX + oh * 96 + ow) * 128 + c4] = o;
}

// ---------------------------------------------------------------------------
// conv2 via MFMA: 3x3 s2 p1 + BN + SiLU. y2b NHWC bf16 -> feat2b NHWC bf16.
// ---------------------------------------------------------------------------
__global__ __launch_bounds__(256) void conv2_mfma_kernel(
    const bf16* __restrict__ y2b, const bf16* __restrict__ W2b,
    const float* __restrict__ b2, bf16* __restrict__ feat2b)
{
  __shared__ bf16 As[64 * LDA];
  __shared__ bf16 Bs[128 * LDA];
  int m0 = blockIdx.x << 6;
  int t = threadIdx.x;
  int wv = t >> 6, lane = t & 63;
  int lrow = lane & 15, q = lane >> 4;
  int n0 = wv * 32;
  f32x4 acc[4][2];
#pragma unroll
  for (int i = 0; i < 4; ++i)
#pragma unroll
    for (int j = 0; j < 2; ++j)
#pragma unroll
      for (int e = 0; e < 4; ++e) acc[i][j][e] = 0.f;
  bf16x8 zv;
#pragma unroll
  for (int e = 0; e < 8; ++e) zv[e] = (bf16)0.f;

  for (int kp = 0; kp < 9; ++kp) {
    int kh = kp / 3, kw = kp - kh * 3;
    __syncthreads();
    for (int i = t; i < 1024; i += 256) {
      int row = i >> 4; int c8 = (i & 15) << 3;
      int m = m0 + row;
      int nimg = m / NPIX; int hw = m - nimg * NPIX;
      int oh = hw / 96, ow = hw - oh * 96;
      int ih = 2 * oh - 1 + kh, iw = 2 * ow - 1 + kw;
      bf16x8 v = zv;
      if ((unsigned)ih < 192u && (unsigned)iw < 192u)
        v = *(const bf16x8*)&y2b[(((size_t)nimg * 192 + ih) * 192 + iw) * 128 + c8];
      *(bf16x8*)&As[row * LDA + c8] = v;
    }
    const bf16* Wk = W2b + kp * 16384;
    for (int i = t; i < 2048; i += 256) {
      int nn = i >> 4; int k8 = (i & 15) << 3;
      *(bf16x8*)&Bs[nn * LDA + k8] = *(const bf16x8*)&Wk[nn * 128 + k8];
    }
    __syncthreads();
#pragma unroll
    for (int ks = 0; ks < 4; ++ks) {
      bf16x8 bfr0 = *(const bf16x8*)&Bs[(n0 + lrow) * LDA + ks * 32 + q * 8];
      bf16x8 bfr1 = *(const bf16x8*)&Bs[(n0 + 16 + lrow) * LDA + ks * 32 + q * 8];
#pragma unroll
      for (int mi = 0; mi < 4; ++mi) {
        bf16x8 afr = *(const bf16x8*)&As[(mi * 16 + lrow) * LDA + ks * 32 + q * 8];
        acc[mi][0] = __builtin_amdgcn_mfma_f32_16x16x32_bf16(afr, bfr0, acc[mi][0], 0, 0, 0);
        acc[mi][1] = __builtin_amdgcn_mfma_f32_16x16x32_bf16(afr, bfr1, acc[mi][1], 0, 0, 0);
      }
    }
  }
#pragma unroll
  for (int mi = 0; mi < 4; ++mi) {
#pragma unroll
    for (int nj = 0; nj < 2; ++nj) {
      int co = n0 + nj * 16 + lrow;
      float bb = b2[co];
#pragma unroll
      for (int r = 0; r < 4; ++r) {
        int m = m0 + mi * 16 + q * 4 + r;
        feat2b[(size_t)m * 128 + co] = (bf16)silu_f(acc[mi][nj][r] + bb);
      }
    }
  }
}

// ---------------------------------------------------------------------------
// Generic bf16 MFMA GEMM (used for input_proj): A bf16 [M][128] @ W [Nc][128]^T
// store_mode 2: bf16 out[m*128+col]
// ---------------------------------------------------------------------------
__global__ __launch_bounds__(256) void mm_bf16_kernel(
    const bf16* __restrict__ A, const bf16* __restrict__ W,
    const float* __restrict__ bias, int Nc, int ostride, int act,
    int store_mode, void* __restrict__ outp)
{
  __shared__ bf16 As[64 * LDA];
  __shared__ bf16 Bs[128 * LDA];
  int m0 = blockIdx.x << 6;
  int nb = blockIdx.y << 7;
  int cols_here = Nc - nb; if (cols_here > 128) cols_here = 128;
  int t = threadIdx.x;
  for (int i = t; i < 1024; i += 256) {
    int row = i >> 4; int c8 = (i & 15) << 3;
    *(bf16x8*)&As[row * LDA + c8] = *(const bf16x8*)&A[(size_t)(m0 + row) * 128 + c8];
  }
  bf16x8 zv;
#pragma unroll
  for (int e = 0; e < 8; ++e) zv[e] = (bf16)0.f;
  for (int i = t; i < 2048; i += 256) {
    int n = i >> 4; int k8 = (i & 15) << 3;
    bf16x8 v = (n < cols_here) ? *(const bf16x8*)&W[(size_t)(nb + n) * 128 + k8] : zv;
    *(bf16x8*)&Bs[n * LDA + k8] = v;
  }
  __syncthreads();

  int wv = t >> 6, lane = t & 63;
  int lrow = lane & 15, q = lane >> 4;
  int n0 = wv * 32;
  f32x4 acc[4][2];
#pragma unroll
  for (int i = 0; i < 4; ++i)
#pragma unroll
    for (int j = 0; j < 2; ++j)
#pragma unroll
      for (int e = 0; e < 4; ++e) acc[i][j][e] = 0.f;

#pragma unroll
  for (int ks = 0; ks < 4; ++ks) {
    bf16x8 bfr0 = *(const bf16x8*)&Bs[(n0 + lrow) * LDA + ks * 32 + q * 8];
    bf16x8 bfr1 = *(const bf16x8*)&Bs[(n0 + 16 + lrow) * LDA + ks * 32 + q * 8];
#pragma unroll
    for (int mi = 0; mi < 4; ++mi) {
      bf16x8 afr = *(const bf16x8*)&As[(mi * 16 + lrow) * LDA + ks * 32 + q * 8];
      acc[mi][0] = __builtin_amdgcn_mfma_f32_16x16x32_bf16(afr, bfr0, acc[mi][0], 0, 0, 0);
      acc[mi][1] = __builtin_amdgcn_mfma_f32_16x16x32_bf16(afr, bfr1, acc[mi][1], 0, 0, 0);
    }
  }

  float* outf = (float*)outp;
  bf16*  outb = (bf16*)outp;
#pragma unroll
  for (int mi = 0; mi < 4; ++mi) {
#pragma unroll
    for (int nj = 0; nj < 2; ++nj) {
      int col = nb + n0 + nj * 16 + lrow;
      if (col >= Nc) continue;
      float bb = bias[col];
#pragma unroll
      for (int r = 0; r < 4; ++r) {
        int m = m0 + mi * 16 + q * 4 + r;
        float v = acc[mi][nj][r] + bb;
        if (act == 1) v = fmaxf(v, 0.f);
        if (store_mode == 0) {
          outf[(size_t)m * ostride + col] = v;
        } else if (store_mode == 2) {
          outb[(size_t)m * 128 + col] = (bf16)v;
        } else {
          int nn = m / NPIX; int hw = m - nn * NPIX;
          int img = nn & 3; int choff = (nn >= 4) ? 256 : 0;
          outf[((size_t)(img * 384 + choff + col)) * NPIX + hw] = v;
        }
      }
    }
  }
}

// ---------------------------------------------------------------------------
// Depthwise 3x3 + bias + LayerNorm + GELU(tanh), bf16 in/out
// block 256 = 16 px x 16 lanes; lane = 8 channels
// ---------------------------------------------------------------------------
__global__ __launch_bounds__(256) void dwln_kernel(
    const bf16* __restrict__ featb, const float* __restrict__ dw_w,
    const float* __restrict__ dw_b, const float* __restrict__ ln_g,
    const float* __restrict__ ln_b, bf16* __restrict__ dwgb)
{
  int t = threadIdx.x;
  int pxl = t >> 4;
  int c8 = (t & 15) << 3;
  int pixel = blockIdx.x * 16 + pxl;
  int n = pixel / NPIX; int hw = pixel - n * NPIX;
  int h = hw / 96; int w = hw - h * 96;
  const bf16* fn = featb + (size_t)n * NPIX * 128 + c8;
  float acc[8];
#pragma unroll
  for (int e = 0; e < 8; ++e) acc[e] = dw_b[c8 + e];
#pragma unroll
  for (int kh = 0; kh < 3; ++kh) {
    int hh = h + kh - 1;
    if ((unsigned)hh >= 96u) continue;
#pragma unroll
    for (int kw = 0; kw < 3; ++kw) {
      int ww = w + kw - 1;
      if ((unsigned)ww >= 96u) continue;
      bf16x8 v = *(const bf16x8*)&fn[(hh * 96 + ww) * 128];
      const float* wt = &dw_w[(kh * 3 + kw) * 128 + c8];
#pragma unroll
      for (int e = 0; e < 8; ++e) acc[e] += (float)v[e] * wt[e];
    }
  }
  float s = 0.f, qs = 0.f;
#pragma unroll
  for (int e = 0; e < 8; ++e) { s += acc[e]; qs += acc[e] * acc[e]; }
#pragma unroll
  for (int off = 8; off > 0; off >>= 1) {
    s  += __shfl_xor(s, off);
    qs += __shfl_xor(qs, off);
  }
  float mean = s * (1.f / 128.f);
  float var = qs * (1.f / 128.f) - mean * mean;
  float rstd = rsqrtf(var + EPSV);
  bf16x8 o;
#pragma unroll
  for (int e = 0; e < 8; ++e) {
    float xn = (acc[e] - mean) * rstd * ln_g[c8 + e] + ln_b[c8 + e];
    float z = 0.7978845608028654f * (xn + 0.044715f * xn * xn * xn);
    float th;
    if (z > 15.f) th = 1.f;
    else if (z < -15.f) th = -1.f;
    else { float e2 = __expf(2.f * z); th = (e2 - 1.f) / (e2 + 1.f); }
    o[e] = (bf16)(0.5f * xn * (1.f + th));
  }
  *(bf16x8*)&dwgb[(size_t)pixel * 128 + c8] = o;
}

// ---------------------------------------------------------------------------
// Fused offset/mask GEMM + softmax + deformable sampling + output_proj GEMM.
// One block = 64 px tile. Phases:
//   1. stage dwg tile into As (bf16 64x128)
//   2. om GEMM (4 chunks of 64 cols) -> S fp16 [col][px] logits (bias added)
//   3. sampling: softmax over 9 taps, bilinear gather from xpb, vagg -> As
//   4. op GEMM (2 chunks of 64 cols) + bias + ReLU -> d_out NCHW (dual-branch)
// LDS = 17408 + 17408 + 29568 = 64384 B -> 2 blocks/CU.
// ---------------------------------------------------------------------------
__global__ __launch_bounds__(256) void omsop_kernel(
    const bf16* __restrict__ dwgb, const bf16* __restrict__ xpb,
    const bf16* __restrict__ Womb, const float* __restrict__ bomf,
    const bf16* __restrict__ Wopb, const float* __restrict__ opb,
    float* __restrict__ out)
{
  __shared__ bf16 As[64 * LDA];
  __shared__ bf16 Bs[64 * LDA];
  __shared__ _Float16 S[224 * SPX];
  int m0 = blockIdx.x << 6;
  int t = threadIdx.x;
  int wv = t >> 6, lane = t & 63;
  int lrow = lane & 15, q = lane >> 4;
  bf16x8 zv;
#pragma unroll
  for (int e = 0; e < 8; ++e) zv[e] = (bf16)0.f;

  // phase 1: stage dwg tile
  for (int i = t; i < 1024; i += 256) {
    int row = i >> 4, c8 = (i & 15) << 3;
    *(bf16x8*)&As[row * LDA + c8] = *(const bf16x8*)&dwgb[(size_t)(m0 + row) * 128 + c8];
  }
  __syncthreads();

  // phase 2: om GEMM, 4 chunks x 64 cols (cols 224..255 discarded)
  for (int c = 0; c < 4; ++c) {
    // stage full 64 rows x 128 k  (1024 x bf16x8)
    for (int i = t; i < 1024; i += 256) {
      int rr = i >> 4, k8 = (i & 15) << 3;
      int gr = c * 64 + rr;
      bf16x8 v = (gr < 224) ? *(const bf16x8*)&Womb[(size_t)gr * 128 + k8] : zv;
      *(bf16x8*)&Bs[rr * LDA + k8] = v;
    }
    __syncthreads();
    f32x4 acc[4];
#pragma unroll
    for (int mi = 0; mi < 4; ++mi)
#pragma unroll
      for (int e = 0; e < 4; ++e) acc[mi][e] = 0.f;
#pragma unroll
    for (int ks = 0; ks < 4; ++ks) {
      bf16x8 bfr = *(const bf16x8*)&Bs[(wv * 16 + lrow) * LDA + ks * 32 + q * 8];
#pragma unroll
      for (int mi = 0; mi < 4; ++mi) {
        bf16x8 afr = *(const bf16x8*)&As[(mi * 16 + lrow) * LDA + ks * 32 + q * 8];
        acc[mi] = __builtin_amdgcn_mfma_f32_16x16x32_bf16(afr, bfr, acc[mi], 0, 0, 0);
      }
    }
    int col = c * 64 + wv * 16 + lrow;
    if (col < 224) {
      float bb = bomf[col];
#pragma unroll
      for (int mi = 0; mi < 4; ++mi)
#pragma unroll
        for (int r = 0; r < 4; ++r)
          S[col * SPX + mi * 16 + q * 4 + r] = (_Float16)(acc[mi][r] + bb);
    }
    __syncthreads();
  }

  // phase 3: sampling — 4 tasks/thread: (px = t>>4 + 16k, g = (t>>1)&7, c8 = (t&1)*8)
  {
    int gg = (t >> 1) & 7;
    int c8s = (t & 1) << 3;
    for (int k = 0; k < 4; ++k) {
      int px = (t >> 4) + (k << 4);
      int pixel = m0 + px;
      int n = pixel / NPIX; int hw = pixel - n * NPIX;
      int h = hw / 96, w = hw - h * 96;
      float lg[9]; float mx = -1e30f;
#pragma unroll
      for (int p = 0; p < 9; ++p) {
        lg[p] = (float)S[(144 + gg * 9 + p) * SPX + px];
        mx = fmaxf(mx, lg[p]);
      }
      float se = 0.f;
#pragma unroll
      for (int p = 0; p < 9; ++p) { lg[p] = __expf(lg[p] - mx); se += lg[p]; }
      float inv = 1.f / se;
      const bf16* xpn = xpb + (size_t)n * NPIX * 128 + gg * 16 + c8s;
      float acc8[8];
#pragma unroll
      for (int e = 0; e < 8; ++e) acc8[e] = 0.f;
#pragma unroll
      for (int p = 0; p < 9; ++p) {
        float dx = (float)S[(gg * 18 + p * 2) * SPX + px];
        float dy = (float)S[(gg * 18 + p * 2 + 1) * SPX + px];
        float pyu = (float)(h + p / 3 - 1) + dy;
        float pxu = (float)(w + p % 3 - 1) + dx;
        float yf = floorf(pyu), xf = floorf(pxu);
        float wy = pyu - yf, wx = pxu - xf;
        int y0 = (int)yf, x0 = (int)xf;
        float ay0 = ((unsigned)y0 < 96u) ? (1.f - wy) : 0.f;
        float ay1 = ((unsigned)(y0 + 1) < 96u) ? wy : 0.f;
        float ax0 = ((unsigned)x0 < 96u) ? (1.f - wx) : 0.f;
        float ax1 = ((unsigned)(x0 + 1) < 96u) ? wx : 0.f;
        int y0c = min(max(y0, 0), 95), y1c = min(max(y0 + 1, 0), 95);
        int x0c = min(max(x0, 0), 95), x1c = min(max(x0 + 1, 0), 95);
        float w00 = ay0 * ax0, w01 = ay0 * ax1, w10 = ay1 * ax0, w11 = ay1 * ax1;
        bf16x8 v00 = *(const bf16x8*)&xpn[(y0c * 96 + x0c) * 128];
        bf16x8 v01 = *(const bf16x8*)&xpn[(y0c * 96 + x1c) * 128];
        bf16x8 v10 = *(const bf16x8*)&xpn[(y1c * 96 + x0c) * 128];
        bf16x8 v11 = *(const bf16x8*)&xpn[(y1c * 96 + x1c) * 128];
        float mp = lg[p] * inv;
#pragma unroll
        for (int e = 0; e < 8; ++e) {
          float sv = w00 * (float)v00[e] + w01 * (float)v01[e]
                   + w10 * (float)v10[e] + w11 * (float)v11[e];
          acc8[e] += mp * sv;
        }
      }
      bf16x8 o;
#pragma unroll
      for (int e = 0; e < 8; ++e) o[e] = (bf16)acc8[e];
      *(bf16x8*)&As[px * LDA + gg * 16 + c8s] = o;   // vagg tile (As reused)
    }
  }
  __syncthreads();

  // phase 4: op GEMM, 2 chunks x 64 cols, + bias + ReLU -> d_out NCHW
  for (int c2 = 0; c2 < 2; ++c2) {
    // stage full 64 rows x 128 k
    for (int i = t; i < 1024; i += 256) {
      int rr = i >> 4, k8 = (i & 15) << 3;
      *(bf16x8*)&Bs[rr * LDA + k8] =
          *(const bf16x8*)&Wopb[(size_t)(c2 * 64 + rr) * 128 + k8];
    }
    __syncthreads();
    f32x4 acc[4];
#pragma unroll
    for (int mi = 0; mi < 4; ++mi)
#pragma unroll
      for (int e = 0; e < 4; ++e) acc[mi][e] = 0.f;
#pragma unroll
    for (int ks = 0; ks < 4; ++ks) {
      bf16x8 bfr = *(const bf16x8*)&Bs[(wv * 16 + lrow) * LDA + ks * 32 + q * 8];
#pragma unroll
      for (int mi = 0; mi < 4; ++mi) {
        bf16x8 afr = *(const bf16x8*)&As[(mi * 16 + lrow) * LDA + ks * 32 + q * 8];
        acc[mi] = __builtin_amdgcn_mfma_f32_16x16x32_bf16(afr, bfr, acc[mi], 0, 0, 0);
      }
    }
    int col = c2 * 64 + wv * 16 + lrow;
    float bb = opb[col];
#pragma unroll
    for (int mi = 0; mi < 4; ++mi) {
#pragma unroll
      for (int r = 0; r < 4; ++r) {
        int m = m0 + mi * 16 + q * 4 + r;
        float v = fmaxf(acc[mi][r] + bb, 0.f);
        int nn = m / NPIX; int hww = m - nn * NPIX;
        int img = nn & 3; int choff = (nn >= 4) ? 256 : 0;
        out[((size_t)(img * 384 + choff + col)) * NPIX + hww] = v;
      }
    }
    __syncthreads();
  }
}

// ---------------------------------------------------------------------------
__global__ __launch_bounds__(256) void copy_x0_kernel(
    const float4* __restrict__ x0, float4* __restrict__ out)
{
  int idx = blockIdx.x * 256 + threadIdx.x;
  int n = idx / (128 * 2304);
  int r = idx - n * (128 * 2304);
  out[(size_t)(n * 384 + 128) * 2304 + r] = x0[(size_t)n * 128 * 2304 + r];
}

// ---------------------------------------------------------------------------
extern "C" void kernel_launch(void* const* d_in, const int* in_sizes, int n_in,
                              void* d_out, int out_size, void* d_ws, size_t ws_size,
                              hipStream_t stream)
{
  (void)in_sizes; (void)n_in; (void)out_size; (void)ws_size;
  const float* x0      = (const float*)d_in[0];
  const float* x1      = (const float*)d_in[1];
  const float* x2      = (const float*)d_in[2];
  const float* conv_w  = (const float*)d_in[3];
  const float* conv_g  = (const float*)d_in[4];
  const float* conv_b  = (const float*)d_in[5];
  const float* conv_rm = (const float*)d_in[6];
  const float* conv_rv = (const float*)d_in[7];
  const float* conv1_w = (const float*)d_in[8];
  const float* conv1_g = (const float*)d_in[9];
  const float* conv1_b = (const float*)d_in[10];
  const float* conv1_rm= (const float*)d_in[11];
  const float* conv1_rv= (const float*)d_in[12];
  const float* conv2_w = (const float*)d_in[13];
  const float* conv2_g = (const float*)d_in[14];
  const float* conv2_b = (const float*)d_in[15];
  const float* conv2_rm= (const float*)d_in[16];
  const float* conv2_rv= (const float*)d_in[17];
  const float* dw_w    = (const float*)d_in[18];
  const float* dw_b    = (const float*)d_in[19];
  const float* ln_g    = (const float*)d_in[20];
  const float* ln_b    = (const float*)d_in[21];
  const float* off_w   = (const float*)d_in[22];
  const float* off_b   = (const float*)d_in[23];
  const float* m_w     = (const float*)d_in[24];
  const float* m_b     = (const float*)d_in[25];
  const float* ip_w    = (const float*)d_in[26];
  const float* ip_b    = (const float*)d_in[27];
  const float* op_w    = (const float*)d_in[28];
  const float* op_b    = (const float*)d_in[29];
  float* out = (float*)d_out;
  char* WS = (char*)d_ws;

  // byte layout
  bf16* featb  = (bf16*)WS;                      // 8 imgs x 9216 px x 128 ch (18.9 MB)
  bf16* feat1b = featb;
  bf16* feat2b = featb + 4718592;
  bf16* y2b    = (bf16*)(WS + 18874368);         // 37.7 MB, dead after conv2
  bf16* xpb    = (bf16*)(WS + 18874368);         // alias (written after conv2)
  bf16* dwgb   = (bf16*)(WS + 37748736);         // 18.9 MB
  bf16* y1b    = (bf16*)(WS + 56623104);         // 2.36 MB, dead after upsample
  float* WTSf  = (float*)(WS + 125042688);       // 608 floats
  bf16*  WTSb  = (bf16*)(WS + 125045120);        // 249856 bf16

  float* b1f  = WTSf;
  float* b1bf = WTSf + 128;
  float* b2f  = WTSf + 256;
  float* bomf = WTSf + 384;
  bf16* W1b  = WTSb;
  bf16* W1bb = WTSb + 32768;
  bf16* W2b  = WTSb + 40960;
  bf16* Wipb = WTSb + 188416;
  bf16* Womb = WTSb + 204800;
  bf16* Wopb = WTSb + 233472;

  prep_kernel<<<979, 256, 0, stream>>>(
      conv_w, conv_g, conv_b, conv_rm, conv_rv,
      conv1_w, conv1_g, conv1_b, conv1_rm, conv1_rv,
      conv2_w, conv2_g, conv2_b, conv2_rm, conv2_rv,
      ip_w, op_w, off_w, m_w, off_b, m_b, WTSf, WTSb);

  // x1 path: 1x1 conv (K=256) -> y1b ; upsample -> feat1b
  c1x1_mfma_kernel<<<144, 256, 0, stream>>>(x1, W1b, b1f, 256, 2304, y1b);
  upsample_kernel<<<4608, 256, 0, stream>>>(y1b, feat1b);

  // x2 path: 1x1 conv (K=64) -> y2b ; 3x3 s2 conv -> feat2b
  c1x1_mfma_kernel<<<2304, 256, 0, stream>>>(x2, W1bb, b1bf, 64, 36864, y2b);
  conv2_mfma_kernel<<<576, 256, 0, stream>>>(y2b, W2b, b2f, feat2b);

  // fused dual-branch DCNv3 (M = 73728)
  mm_bf16_kernel<<<dim3(1152, 1), 256, 0, stream>>>(featb, Wipb, ip_b, 128, 128, 0, 2, xpb);
  dwln_kernel<<<4608, 256, 0, stream>>>(featb, dw_w, dw_b, ln_g, ln_b, dwgb);
  omsop_kernel<<<1152, 256, 0, stream>>>(dwgb, xpb, Womb, bomf, Wopb, op_b, out);

  copy_x0_kernel<<<4608, 256, 0, stream>>>((const float4*)x0, (float4*)out);
}